// Round 1
// 125.675 us; speedup vs baseline: 1.0445x; 1.0445x over previous
//
#include <hip/hip_runtime.h>
#include <hip/hip_bf16.h>

#define HWP 9216   // H*W
#define HH  96
#define WW  96
#define CC  256    // Cin == Cout
#define NB  2

typedef __attribute__((ext_vector_type(8))) short bf16x8;
typedef __attribute__((ext_vector_type(4))) float f32x4;

__device__ inline unsigned short f2bf(float f) {
  union { __hip_bfloat16 h; unsigned short u; } cvt;
  cvt.h = __float2bfloat16(f);
  return cvt.u;
}
__device__ inline float bf_lo(unsigned int u) { return __uint_as_float(u << 16); }
__device__ inline float bf_hi(unsigned int u) { return __uint_as_float(u & 0xffff0000u); }

// ---- prep: pw_w (256x256) f32->bf16 ; off_w (18x256) f32->bf16 zero-padded to
// (32x256) ; dw_w (256x9) f32 -> transposed dwt (9x256) f32
__global__ __launch_bounds__(256) void k_prep(const float* __restrict__ pw,
                                              const float* __restrict__ ow,
                                              const float* __restrict__ dw,
                                              unsigned short* __restrict__ pwb,
                                              unsigned short* __restrict__ wb,
                                              float* __restrict__ dwt) {
  int i = (blockIdx.x * 256 + threadIdx.x) * 4;
  if (i < CC * CC) {
    float4 v = *(const float4*)(pw + i);
    ushort4 o = make_ushort4(f2bf(v.x), f2bf(v.y), f2bf(v.z), f2bf(v.w));
    *(ushort4*)(pwb + i) = o;
  } else if (i < CC * CC + 32 * 256) {
    int j = i - CC * CC;           // 0..8191
    int row = j >> 8;
    ushort4 o = make_ushort4(0, 0, 0, 0);
    if (row < 18) {
      float4 v = *(const float4*)(ow + j);
      o = make_ushort4(f2bf(v.x), f2bf(v.y), f2bf(v.z), f2bf(v.w));
    }
    *(ushort4*)(wb + j) = o;
  } else {
    int j2 = i - (CC * CC + 32 * 256);   // 0..2303 (step 4)
    if (j2 < 9 * 256) {
      int kk = j2 >> 8;
      int ch = j2 & 255;
      float4 v = make_float4(dw[(ch + 0) * 9 + kk], dw[(ch + 1) * 9 + kk],
                             dw[(ch + 2) * 9 + kk], dw[(ch + 3) * 9 + kk]);
      *(float4*)(dwt + j2) = v;
    }
  }
}

// ---- fused: xp = pw_w . x  (bf16 MFMA, 32 pix x 256 ch per block, BK=32)
//            + offs = off_w . xp + off_b  (MFMA epilogue on the Cs tile)
// 1-D grid, XCD-aligned: block g -> XCD class e=g%8 produces pixel strip
// [e*1152, (e+1)*1152) per batch, so k_gather (same decode) finds xp in the
// LOCAL per-XCD L2. Pitfalls: register-prefetch pipelining (R6/R7) REGRESSED;
// BK=64 (R9) REGRESSED — LDS 58KB halves blocks/CU. Keep BK=32.
__global__ __launch_bounds__(256) void k_main(const float* __restrict__ x,
                                              const unsigned short* __restrict__ pwb,
                                              const unsigned short* __restrict__ wb,
                                              const float* __restrict__ off_b,
                                              unsigned short* __restrict__ xpb,
                                              float* __restrict__ offs) {
  __shared__ unsigned short As[32 * 40];    // [pix][k]
  __shared__ unsigned short Bs[256 * 40];   // [n][k]
  __shared__ unsigned short Cs[32 * 264];   // [pix][ch] bf16, pad 264

  // XCD-aligned decode: g -> (e, b, m); strip block x = e*36 + m
  int g   = blockIdx.x;          // 0..575
  int e   = g & 7;
  int idx = g >> 3;              // 0..71
  int b   = idx / 36;
  int m   = idx - b * 36;        // 0..35
  int pix0 = (e * 36 + m) * 32;  // local pixel within batch

  int t    = threadIdx.x;
  int lane = t & 63;
  int w    = t >> 6;
  int mw = (w & 1) * 16;     // wave pixel tile
  int nw = (w >> 1) * 128;   // wave channel half
  int r = lane & 15, q = lane >> 4;

  f32x4 acc[8] = {};

  const float* xg = x + (size_t)b * CC * HWP + pix0;
  int sc = t >> 3;           // channel within 32-chunk
  int sp = (t & 7) * 4;      // pixel offset

  for (int k0 = 0; k0 < CC; k0 += 32) {
    // A: coalesced float4 (4 pixels, 1 channel) -> in-register cvt -> transposed LDS
    f32x4 xv = __builtin_nontemporal_load((const f32x4*)(xg + (size_t)(k0 + sc) * HWP + sp));
    As[(sp + 0) * 40 + sc] = f2bf(xv.x);
    As[(sp + 1) * 40 + sc] = f2bf(xv.y);
    As[(sp + 2) * 40 + sc] = f2bf(xv.z);
    As[(sp + 3) * 40 + sc] = f2bf(xv.w);
    // B: 256 rows x 32 k slice of pwb
    const unsigned short* bg = pwb + k0;
#pragma unroll
    for (int rep = 0; rep < 4; ++rep) {
      int n  = rep * 64 + (t >> 2);
      int c8 = (t & 3) * 8;
      *(uint4*)&Bs[n * 40 + c8] = *(const uint4*)(bg + n * 256 + c8);
    }
    __syncthreads();
    bf16x8 a = *(const bf16x8*)&As[(mw + r) * 40 + q * 8];
#pragma unroll
    for (int nt = 0; nt < 8; ++nt) {
      bf16x8 bb = *(const bf16x8*)&Bs[(nw + nt * 16 + r) * 40 + q * 8];
      acc[nt] = __builtin_amdgcn_mfma_f32_16x16x32_bf16(a, bb, acc[nt], 0, 0, 0);
    }
    __syncthreads();
  }

  // C/D: col = lane&15 (ch), row = q*4+rr (pix) -> Cs[pix][ch] bf16
#pragma unroll
  for (int nt = 0; nt < 8; ++nt)
#pragma unroll
    for (int rr = 0; rr < 4; ++rr)
      Cs[(mw + q * 4 + rr) * 264 + nw + nt * 16 + r] = f2bf(acc[nt][rr]);
  __syncthreads();

  // write xpb coalesced: 64 B contiguous per thread
  {
    int pix = t >> 3, c32 = (t & 7) * 32;
    unsigned short* o = xpb + ((size_t)b * HWP + pix0 + pix) * CC + c32;
#pragma unroll
    for (int j = 0; j < 4; ++j)
      *(uint4*)(o + j * 8) = *(const uint4*)&Cs[pix * 264 + c32 + j * 8];
  }

  // offset epilogue: offs[pix, o] = sum_c Cs[pix][c] * wb[o][c] + off_b[o]
  {
    int mw2 = (w & 1) * 16;    // pixel tile
    int nw2 = (w >> 1) * 16;   // o tile (0 or 16)
    f32x4 oacc = {};
#pragma unroll
    for (int ks = 0; ks < CC; ks += 32) {
      bf16x8 a = *(const bf16x8*)&Cs[(mw2 + r) * 264 + ks + q * 8];
      uint4 u = *(const uint4*)(wb + (nw2 + r) * 256 + ks + q * 8);
      bf16x8 bb;
      ((uint4*)&bb)[0] = u;
      oacc = __builtin_amdgcn_mfma_f32_16x16x32_bf16(a, bb, oacc, 0, 0, 0);
    }
    int o = nw2 + r;
    if (o < 18) {
      float ob = off_b[o];
      size_t base = ((size_t)b * HWP + pix0 + mw2 + q * 4) * 20 + o;
#pragma unroll
      for (int rr = 0; rr < 4; ++rr)
        offs[base + (size_t)rr * 20] = oacc[rr] + ob;
    }
  }
}

// ---- gather + depthwise: 16 pixels/block, XCD-ALIGNED to k_main's strips.
// R10: per-(pixel,tap) bilinear decode (offs load + floor/clamp/weights, ~60
// VALU) was replicated across all 64 lanes of a wave (lanes differ only in
// channel). Now a 144-thread precompute phase stores {weights float4, corner
// byte-offsets int4} to LDS once per block; main loop reads them via
// broadcast ds_read_b128 (same-address -> conflict-free) and does only the
// per-channel work (unpack + FMA). Also removes the per-iteration dependent
// offs VMEM load from the inner loop.
// Hard-won pitfalls:
//  * NO launch-bounds min-wave arg (R6: forced VGPR 64 -> scratch spills, 3x)
//  * NO nontemporal output stores (R4: 4x WRITE_SIZE amplification)
//  * NO 8-ch/lane half-wave scheme (R8: VGPR 176, occupancy 9%, +25% time)
__global__ __launch_bounds__(256) void k_gather(const unsigned short* __restrict__ xp,
                                                const float* __restrict__ offs,
                                                const float* __restrict__ dwt,
                                                float* __restrict__ out) {
  __shared__ float Cs[16][257];
  __shared__ float4 Wt[16][9];   // bilinear weights per (pixel, tap)
  __shared__ int4   Ad[16][9];   // corner row byte-offsets per (pixel, tap)

  // XCD-aligned decode: g -> (e, b, m2); chunk c = e*72 + m2 (16 px each)
  int g   = blockIdx.x;          // 0..1151
  int e   = g & 7;
  int idx = g >> 3;              // 0..143
  int b   = idx / 72;
  int m2  = idx - b * 72;        // 0..71
  int c   = e * 72 + m2;         // 0..575
  int pix0 = b * HWP + c * 16;   // global pixel

  int wave = threadIdx.x >> 6;
  int lane = threadIdx.x & 63;
  int c0 = lane * 4;

  int hw0 = pix0 - b * HWP;
  const unsigned short* xb = xp + (size_t)b * HWP * CC;
  const float* opb = offs + (size_t)pix0 * 20;

  // ---- phase 0: 144 threads compute the wave-uniform per-(pixel,tap) data once
  {
    int tp = threadIdx.x;
    if (tp < 144) {
      int ip = tp / 9;               // pixel 0..15
      int kk = tp - ip * 9;          // tap 0..8
      int hw = hw0 + ip;
      int h = hw / WW;
      int wq = hw - h * WW;
      float2 o2 = *(const float2*)(opb + ip * 20 + 2 * kk);
      float y = (float)(h + kk / 3 - 1) + o2.x;
      float x = (float)(wq + kk % 3 - 1) + o2.y;
      float y0f = floorf(y), x0f = floorf(x);
      float fy = y - y0f, fx = x - x0f;
      int y0 = (int)y0f, x0 = (int)x0f;
      int y1 = y0 + 1, x1 = x0 + 1;
      bool vy0 = (y0 >= 0) & (y0 < HH);
      bool vy1 = (y1 >= 0) & (y1 < HH);
      bool vx0 = (x0 >= 0) & (x0 < WW);
      bool vx1 = (x1 >= 0) & (x1 < WW);
      int y0c = y0 < 0 ? 0 : (y0 > HH - 1 ? HH - 1 : y0);
      int y1c = y1 < 0 ? 0 : (y1 > HH - 1 ? HH - 1 : y1);
      int x0c = x0 < 0 ? 0 : (x0 > WW - 1 ? WW - 1 : x0);
      int x1c = x1 < 0 ? 0 : (x1 > WW - 1 ? WW - 1 : x1);
      Wt[ip][kk] = make_float4(
          (1.f - fy) * (1.f - fx) * ((vy0 && vx0) ? 1.f : 0.f),
          (1.f - fy) * fx         * ((vy0 && vx1) ? 1.f : 0.f),
          fy * (1.f - fx)         * ((vy1 && vx0) ? 1.f : 0.f),
          fy * fx                 * ((vy1 && vx1) ? 1.f : 0.f));
      Ad[ip][kk] = make_int4((y0c * WW + x0c) * (CC * 2), (y0c * WW + x1c) * (CC * 2),
                             (y1c * WW + x0c) * (CC * 2), (y1c * WW + x1c) * (CC * 2));
    }
  }
  __syncthreads();

  // ---- main loop: per-channel work only (unpack + FMA); addresses/weights
  // come from LDS broadcast reads.
  const char* xbc = (const char*)xb;
  unsigned lb = (unsigned)(lane * 8);   // this lane's 4-channel byte offset

  float acc[4][4] = {};
#pragma unroll
  for (int kk = 0; kk < 9; ++kk) {
    float4 dv = *(const float4*)(dwt + kk * 256 + c0);
#pragma unroll
    for (int p4 = 0; p4 < 4; ++p4) {
      int ip = wave * 4 + p4;
      float4 wv = Wt[ip][kk];
      int4 av = Ad[ip][kk];
      uint2 u00 = *(const uint2*)(xbc + ((unsigned)av.x + lb));
      uint2 u01 = *(const uint2*)(xbc + ((unsigned)av.y + lb));
      uint2 u10 = *(const uint2*)(xbc + ((unsigned)av.z + lb));
      uint2 u11 = *(const uint2*)(xbc + ((unsigned)av.w + lb));

      float s0 = wv.x * bf_lo(u00.x) + wv.y * bf_lo(u01.x) + wv.z * bf_lo(u10.x) + wv.w * bf_lo(u11.x);
      float s1 = wv.x * bf_hi(u00.x) + wv.y * bf_hi(u01.x) + wv.z * bf_hi(u10.x) + wv.w * bf_hi(u11.x);
      float s2 = wv.x * bf_lo(u00.y) + wv.y * bf_lo(u01.y) + wv.z * bf_lo(u10.y) + wv.w * bf_lo(u11.y);
      float s3 = wv.x * bf_hi(u00.y) + wv.y * bf_hi(u01.y) + wv.z * bf_hi(u10.y) + wv.w * bf_hi(u11.y);

      acc[p4][0] += dv.x * s0;
      acc[p4][1] += dv.y * s1;
      acc[p4][2] += dv.z * s2;
      acc[p4][3] += dv.w * s3;
    }
  }
#pragma unroll
  for (int p4 = 0; p4 < 4; ++p4)
    *(float4*)&Cs[wave * 4 + p4][c0] =
        make_float4(acc[p4][0], acc[p4][1], acc[p4][2], acc[p4][3]);
  __syncthreads();
  // write-out: thread t = channel, 16 consecutive pixels = 64 B contiguous per thread.
  int ch = threadIdx.x;
  float* ob = out + (size_t)b * CC * HWP + (size_t)ch * HWP + hw0;
#pragma unroll
  for (int p4 = 0; p4 < 4; ++p4) {
    float4 v = make_float4(Cs[p4 * 4 + 0][ch], Cs[p4 * 4 + 1][ch],
                           Cs[p4 * 4 + 2][ch], Cs[p4 * 4 + 3][ch]);
    *(float4*)(ob + p4 * 4) = v;
  }
}

extern "C" void kernel_launch(void* const* d_in, const int* in_sizes, int n_in,
                              void* d_out, int out_size, void* d_ws, size_t ws_size,
                              hipStream_t stream) {
  (void)in_sizes; (void)n_in; (void)out_size; (void)ws_size;
  const float* x     = (const float*)d_in[0];
  const float* pw_w  = (const float*)d_in[1];
  const float* off_w = (const float*)d_in[2];
  const float* off_b = (const float*)d_in[3];
  const float* dw_w  = (const float*)d_in[4];
  float* out = (float*)d_out;

  char* ws = (char*)d_ws;
  unsigned short* xpb = (unsigned short*)ws;                 // B*HW*C bf16 = 9,437,184 B
  float* offs = (float*)(ws + 9437184);                      // B*HW*20 f32 = 1,474,560 B
  unsigned short* wb  = (unsigned short*)(ws + 10911744);    // 32*256 bf16 = 16,384 B
  unsigned short* pwb = (unsigned short*)(ws + 10928128);    // 256*256 bf16 = 131,072 B
  float* dwt          = (float*)(ws + 11059200);             // 9*256 f32 = 9,216 B

  k_prep <<<75, 256, 0, stream>>>(pw_w, off_w, dw_w, pwb, wb, dwt);
  k_main <<<576, 256, 0, stream>>>(x, pwb, wb, off_b, xpb, offs);
  k_gather<<<1152, 256, 0, stream>>>(xpb, offs, dwt, out);
}

// Round 2
// 124.623 us; speedup vs baseline: 1.0534x; 1.0084x over previous
//
#include <hip/hip_runtime.h>
#include <hip/hip_bf16.h>

#define HWP 9216   // H*W
#define HH  96
#define WW  96
#define CC  256    // Cin == Cout
#define NB  2

typedef __attribute__((ext_vector_type(8))) short bf16x8;
typedef __attribute__((ext_vector_type(4))) float f32x4;

__device__ inline unsigned short f2bf(float f) {
  union { __hip_bfloat16 h; unsigned short u; } cvt;
  cvt.h = __float2bfloat16(f);
  return cvt.u;
}
__device__ inline float bf_lo(unsigned int u) { return __uint_as_float(u << 16); }
__device__ inline float bf_hi(unsigned int u) { return __uint_as_float(u & 0xffff0000u); }

// ---- prep: pw_w (256x256) f32->bf16 ; off_w (18x256) f32->bf16 zero-padded to
// (32x256) ; dw_w (256x9) f32 -> transposed dwt (9x256) f32
__global__ __launch_bounds__(256) void k_prep(const float* __restrict__ pw,
                                              const float* __restrict__ ow,
                                              const float* __restrict__ dw,
                                              unsigned short* __restrict__ pwb,
                                              unsigned short* __restrict__ wb,
                                              float* __restrict__ dwt) {
  int i = (blockIdx.x * 256 + threadIdx.x) * 4;
  if (i < CC * CC) {
    float4 v = *(const float4*)(pw + i);
    ushort4 o = make_ushort4(f2bf(v.x), f2bf(v.y), f2bf(v.z), f2bf(v.w));
    *(ushort4*)(pwb + i) = o;
  } else if (i < CC * CC + 32 * 256) {
    int j = i - CC * CC;           // 0..8191
    int row = j >> 8;
    ushort4 o = make_ushort4(0, 0, 0, 0);
    if (row < 18) {
      float4 v = *(const float4*)(ow + j);
      o = make_ushort4(f2bf(v.x), f2bf(v.y), f2bf(v.z), f2bf(v.w));
    }
    *(ushort4*)(wb + j) = o;
  } else {
    int j2 = i - (CC * CC + 32 * 256);   // 0..2303 (step 4)
    if (j2 < 9 * 256) {
      int kk = j2 >> 8;
      int ch = j2 & 255;
      float4 v = make_float4(dw[(ch + 0) * 9 + kk], dw[(ch + 1) * 9 + kk],
                             dw[(ch + 2) * 9 + kk], dw[(ch + 3) * 9 + kk]);
      *(float4*)(dwt + j2) = v;
    }
  }
}

// ---- fused: xp = pw_w . x  (bf16 MFMA, 32 pix x 256 ch per block, BK=32)
//            + offs = off_w . xp + off_b  (MFMA epilogue on the Cs tile)
// R11: 2-phase double-buffered pipeline (T3-minimum + T14). One barrier per
// K-step (was 2): issue global loads for step t+1 into regs FIRST, run step
// t's ds_read+MFMA under the load latency, ds_write staged regs to the other
// buffer, single __syncthreads(). Cs aliases Bs[0] (16.9KB <= 20.5KB; safe
// after final sync since last K-step reads buf 1). LDS 45KB -> 3 blocks/CU
// (grid-limited 2.25, so no occupancy loss).
// Pitfalls kept: register-prefetch pipelining of the MFMA frags (R6/R7)
// REGRESSED; BK=64 (R9) REGRESSED. Keep BK=32, pad-40 B layout (2-way=free).
__global__ __launch_bounds__(256) void k_main(const float* __restrict__ x,
                                              const unsigned short* __restrict__ pwb,
                                              const unsigned short* __restrict__ wb,
                                              const float* __restrict__ off_b,
                                              unsigned short* __restrict__ xpb,
                                              float* __restrict__ offs) {
  __shared__ unsigned short As[2][32 * 40];    // [pix][k] dbuf
  __shared__ unsigned short Bs[2][256 * 40];   // [n][k] dbuf; Bs[0] reused as Cs

  // XCD-aligned decode: g -> (e, b, m); strip block x = e*36 + m
  int g   = blockIdx.x;          // 0..575
  int e   = g & 7;
  int idx = g >> 3;              // 0..71
  int b   = idx / 36;
  int m   = idx - b * 36;        // 0..35
  int pix0 = (e * 36 + m) * 32;  // local pixel within batch

  int t    = threadIdx.x;
  int lane = t & 63;
  int w    = t >> 6;
  int mw = (w & 1) * 16;     // wave pixel tile
  int nw = (w >> 1) * 128;   // wave channel half
  int r = lane & 15, q = lane >> 4;

  f32x4 acc[8] = {};

  const float* xg = x + (size_t)b * CC * HWP + pix0;
  int sc = t >> 3;           // channel within 32-chunk
  int sp = (t & 7) * 4;      // pixel offset

  // ---- prologue: stage K-step 0 into buf 0
  {
    f32x4 xv = __builtin_nontemporal_load((const f32x4*)(xg + (size_t)sc * HWP + sp));
    As[0][(sp + 0) * 40 + sc] = f2bf(xv.x);
    As[0][(sp + 1) * 40 + sc] = f2bf(xv.y);
    As[0][(sp + 2) * 40 + sc] = f2bf(xv.z);
    As[0][(sp + 3) * 40 + sc] = f2bf(xv.w);
#pragma unroll
    for (int rep = 0; rep < 4; ++rep) {
      int n  = rep * 64 + (t >> 2);
      int c8 = (t & 3) * 8;
      *(uint4*)&Bs[0][n * 40 + c8] = *(const uint4*)(pwb + n * 256 + c8);
    }
  }
  __syncthreads();

  // ---- main loop: 1 barrier per K-step, prefetch t+1 overlapped with MFMA(t)
  for (int kt = 0; kt < 8; ++kt) {
    int cur = kt & 1;
    f32x4 xv;
    uint4 bu[4];
    bool pre = (kt < 7);
    if (pre) {
      int k0 = (kt + 1) * 32;
      xv = __builtin_nontemporal_load((const f32x4*)(xg + (size_t)(k0 + sc) * HWP + sp));
#pragma unroll
      for (int rep = 0; rep < 4; ++rep) {
        int n  = rep * 64 + (t >> 2);
        int c8 = (t & 3) * 8;
        bu[rep] = *(const uint4*)(pwb + n * 256 + k0 + c8);
      }
    }
    bf16x8 a = *(const bf16x8*)&As[cur][(mw + r) * 40 + q * 8];
#pragma unroll
    for (int nt = 0; nt < 8; ++nt) {
      bf16x8 bb = *(const bf16x8*)&Bs[cur][(nw + nt * 16 + r) * 40 + q * 8];
      acc[nt] = __builtin_amdgcn_mfma_f32_16x16x32_bf16(a, bb, acc[nt], 0, 0, 0);
    }
    if (pre) {
      int nx = cur ^ 1;
      As[nx][(sp + 0) * 40 + sc] = f2bf(xv.x);
      As[nx][(sp + 1) * 40 + sc] = f2bf(xv.y);
      As[nx][(sp + 2) * 40 + sc] = f2bf(xv.z);
      As[nx][(sp + 3) * 40 + sc] = f2bf(xv.w);
#pragma unroll
      for (int rep = 0; rep < 4; ++rep) {
        int n  = rep * 64 + (t >> 2);
        int c8 = (t & 3) * 8;
        *(uint4*)&Bs[nx][n * 40 + c8] = bu[rep];
      }
    }
    __syncthreads();
  }

  // Cs aliases Bs[0]: last K-step read buf 1, and the final sync above makes
  // all reads of buf 0 complete before these writes.
  unsigned short* Cs = &Bs[0][0];   // [pix][ch] bf16, pad 264 (8448 <= 10240 shorts)

  // C/D: col = lane&15 (ch), row = q*4+rr (pix) -> Cs[pix][ch] bf16
#pragma unroll
  for (int nt = 0; nt < 8; ++nt)
#pragma unroll
    for (int rr = 0; rr < 4; ++rr)
      Cs[(mw + q * 4 + rr) * 264 + nw + nt * 16 + r] = f2bf(acc[nt][rr]);
  __syncthreads();

  // write xpb coalesced: 64 B contiguous per thread
  {
    int pix = t >> 3, c32 = (t & 7) * 32;
    unsigned short* o = xpb + ((size_t)b * HWP + pix0 + pix) * CC + c32;
#pragma unroll
    for (int j = 0; j < 4; ++j)
      *(uint4*)(o + j * 8) = *(const uint4*)&Cs[pix * 264 + c32 + j * 8];
  }

  // offset epilogue: offs[pix, o] = sum_c Cs[pix][c] * wb[o][c] + off_b[o]
  {
    int mw2 = (w & 1) * 16;    // pixel tile
    int nw2 = (w >> 1) * 16;   // o tile (0 or 16)
    f32x4 oacc = {};
#pragma unroll
    for (int ks = 0; ks < CC; ks += 32) {
      bf16x8 a = *(const bf16x8*)&Cs[(mw2 + r) * 264 + ks + q * 8];
      uint4 u = *(const uint4*)(wb + (nw2 + r) * 256 + ks + q * 8);
      bf16x8 bb;
      ((uint4*)&bb)[0] = u;
      oacc = __builtin_amdgcn_mfma_f32_16x16x32_bf16(a, bb, oacc, 0, 0, 0);
    }
    int o = nw2 + r;
    if (o < 18) {
      float ob = off_b[o];
      size_t base = ((size_t)b * HWP + pix0 + mw2 + q * 4) * 20 + o;
#pragma unroll
      for (int rr = 0; rr < 4; ++rr)
        offs[base + (size_t)rr * 20] = oacc[rr] + ob;
    }
  }
}

// ---- gather + depthwise: 16 pixels/block, XCD-ALIGNED to k_main's strips.
// R10: per-(pixel,tap) bilinear decode (offs load + floor/clamp/weights, ~60
// VALU) was replicated across all 64 lanes of a wave (lanes differ only in
// channel). Now a 144-thread precompute phase stores {weights float4, corner
// byte-offsets int4} to LDS once per block; main loop reads them via
// broadcast ds_read_b128 (same-address -> conflict-free) and does only the
// per-channel work (unpack + FMA). Also removes the per-iteration dependent
// offs VMEM load from the inner loop.
// Hard-won pitfalls:
//  * NO launch-bounds min-wave arg (R6: forced VGPR 64 -> scratch spills, 3x)
//  * NO nontemporal output stores (R4: 4x WRITE_SIZE amplification)
//  * NO 8-ch/lane half-wave scheme (R8: VGPR 176, occupancy 9%, +25% time)
__global__ __launch_bounds__(256) void k_gather(const unsigned short* __restrict__ xp,
                                                const float* __restrict__ offs,
                                                const float* __restrict__ dwt,
                                                float* __restrict__ out) {
  __shared__ float Cs[16][257];
  __shared__ float4 Wt[16][9];   // bilinear weights per (pixel, tap)
  __shared__ int4   Ad[16][9];   // corner row byte-offsets per (pixel, tap)

  // XCD-aligned decode: g -> (e, b, m2); chunk c = e*72 + m2 (16 px each)
  int g   = blockIdx.x;          // 0..1151
  int e   = g & 7;
  int idx = g >> 3;              // 0..143
  int b   = idx / 72;
  int m2  = idx - b * 72;        // 0..71
  int c   = e * 72 + m2;         // 0..575
  int pix0 = b * HWP + c * 16;   // global pixel

  int wave = threadIdx.x >> 6;
  int lane = threadIdx.x & 63;
  int c0 = lane * 4;

  int hw0 = pix0 - b * HWP;
  const unsigned short* xb = xp + (size_t)b * HWP * CC;
  const float* opb = offs + (size_t)pix0 * 20;

  // ---- phase 0: 144 threads compute the wave-uniform per-(pixel,tap) data once
  {
    int tp = threadIdx.x;
    if (tp < 144) {
      int ip = tp / 9;               // pixel 0..15
      int kk = tp - ip * 9;          // tap 0..8
      int hw = hw0 + ip;
      int h = hw / WW;
      int wq = hw - h * WW;
      float2 o2 = *(const float2*)(opb + ip * 20 + 2 * kk);
      float y = (float)(h + kk / 3 - 1) + o2.x;
      float x = (float)(wq + kk % 3 - 1) + o2.y;
      float y0f = floorf(y), x0f = floorf(x);
      float fy = y - y0f, fx = x - x0f;
      int y0 = (int)y0f, x0 = (int)x0f;
      int y1 = y0 + 1, x1 = x0 + 1;
      bool vy0 = (y0 >= 0) & (y0 < HH);
      bool vy1 = (y1 >= 0) & (y1 < HH);
      bool vx0 = (x0 >= 0) & (x0 < WW);
      bool vx1 = (x1 >= 0) & (x1 < WW);
      int y0c = y0 < 0 ? 0 : (y0 > HH - 1 ? HH - 1 : y0);
      int y1c = y1 < 0 ? 0 : (y1 > HH - 1 ? HH - 1 : y1);
      int x0c = x0 < 0 ? 0 : (x0 > WW - 1 ? WW - 1 : x0);
      int x1c = x1 < 0 ? 0 : (x1 > WW - 1 ? WW - 1 : x1);
      Wt[ip][kk] = make_float4(
          (1.f - fy) * (1.f - fx) * ((vy0 && vx0) ? 1.f : 0.f),
          (1.f - fy) * fx         * ((vy0 && vx1) ? 1.f : 0.f),
          fy * (1.f - fx)         * ((vy1 && vx0) ? 1.f : 0.f),
          fy * fx                 * ((vy1 && vx1) ? 1.f : 0.f));
      Ad[ip][kk] = make_int4((y0c * WW + x0c) * (CC * 2), (y0c * WW + x1c) * (CC * 2),
                             (y1c * WW + x0c) * (CC * 2), (y1c * WW + x1c) * (CC * 2));
    }
  }
  __syncthreads();

  // ---- main loop: per-channel work only (unpack + FMA); addresses/weights
  // come from LDS broadcast reads.
  const char* xbc = (const char*)xb;
  unsigned lb = (unsigned)(lane * 8);   // this lane's 4-channel byte offset

  float acc[4][4] = {};
#pragma unroll
  for (int kk = 0; kk < 9; ++kk) {
    float4 dv = *(const float4*)(dwt + kk * 256 + c0);
#pragma unroll
    for (int p4 = 0; p4 < 4; ++p4) {
      int ip = wave * 4 + p4;
      float4 wv = Wt[ip][kk];
      int4 av = Ad[ip][kk];
      uint2 u00 = *(const uint2*)(xbc + ((unsigned)av.x + lb));
      uint2 u01 = *(const uint2*)(xbc + ((unsigned)av.y + lb));
      uint2 u10 = *(const uint2*)(xbc + ((unsigned)av.z + lb));
      uint2 u11 = *(const uint2*)(xbc + ((unsigned)av.w + lb));

      float s0 = wv.x * bf_lo(u00.x) + wv.y * bf_lo(u01.x) + wv.z * bf_lo(u10.x) + wv.w * bf_lo(u11.x);
      float s1 = wv.x * bf_hi(u00.x) + wv.y * bf_hi(u01.x) + wv.z * bf_hi(u10.x) + wv.w * bf_hi(u11.x);
      float s2 = wv.x * bf_lo(u00.y) + wv.y * bf_lo(u01.y) + wv.z * bf_lo(u10.y) + wv.w * bf_lo(u11.y);
      float s3 = wv.x * bf_hi(u00.y) + wv.y * bf_hi(u01.y) + wv.z * bf_hi(u10.y) + wv.w * bf_hi(u11.y);

      acc[p4][0] += dv.x * s0;
      acc[p4][1] += dv.y * s1;
      acc[p4][2] += dv.z * s2;
      acc[p4][3] += dv.w * s3;
    }
  }
#pragma unroll
  for (int p4 = 0; p4 < 4; ++p4)
    *(float4*)&Cs[wave * 4 + p4][c0] =
        make_float4(acc[p4][0], acc[p4][1], acc[p4][2], acc[p4][3]);
  __syncthreads();
  // write-out: thread t = channel, 16 consecutive pixels = 64 B contiguous per thread.
  int ch = threadIdx.x;
  float* ob = out + (size_t)b * CC * HWP + (size_t)ch * HWP + hw0;
#pragma unroll
  for (int p4 = 0; p4 < 4; ++p4) {
    float4 v = make_float4(Cs[p4 * 4 + 0][ch], Cs[p4 * 4 + 1][ch],
                           Cs[p4 * 4 + 2][ch], Cs[p4 * 4 + 3][ch]);
    *(float4*)(ob + p4 * 4) = v;
  }
}

extern "C" void kernel_launch(void* const* d_in, const int* in_sizes, int n_in,
                              void* d_out, int out_size, void* d_ws, size_t ws_size,
                              hipStream_t stream) {
  (void)in_sizes; (void)n_in; (void)out_size; (void)ws_size;
  const float* x     = (const float*)d_in[0];
  const float* pw_w  = (const float*)d_in[1];
  const float* off_w = (const float*)d_in[2];
  const float* off_b = (const float*)d_in[3];
  const float* dw_w  = (const float*)d_in[4];
  float* out = (float*)d_out;

  char* ws = (char*)d_ws;
  unsigned short* xpb = (unsigned short*)ws;                 // B*HW*C bf16 = 9,437,184 B
  float* offs = (float*)(ws + 9437184);                      // B*HW*20 f32 = 1,474,560 B
  unsigned short* wb  = (unsigned short*)(ws + 10911744);    // 32*256 bf16 = 16,384 B
  unsigned short* pwb = (unsigned short*)(ws + 10928128);    // 256*256 bf16 = 131,072 B
  float* dwt          = (float*)(ws + 11059200);             // 9*256 f32 = 9,216 B

  k_prep <<<75, 256, 0, stream>>>(pw_w, off_w, dw_w, pwb, wb, dwt);
  k_main <<<576, 256, 0, stream>>>(x, pwb, wb, off_b, xpb, offs);
  k_gather<<<1152, 256, 0, stream>>>(xpb, offs, dwt, out);
}